// Round 7
// baseline (272.604 us; speedup 1.0000x reference)
//
#include <hip/hip_runtime.h>

// BilateralGrid apply.
// R1: LDS fp16 gather (118). R2: pk_fma_f16 (103). R3: padded b64 (90;
// conflicts 3.2e7->2.58e7). R4: b128 split layout (conflicts 1.295e7) but
// VGPR clamp => spills => 127. R6: clamp off: 103, latency-bound. R7: quad
// prefetch: 88.5. R8: corner-pipeline: 87.5 (no change — compiler already
// schedules it; source-level reordering inert).
// Model fitting R3/R7/R8: dur ~= LDS_pipe_cy + VALU_cy (pipes serialize;
// conflicts at the statistical floor for random-z gather: ~8.3 cy/instr
// birthday collisions of z0 over 8 bank groups — layout can't fix data
// randomness). Only lever left: REMOVE work from the LDS pipe.
// R9: offload B (row 2; 4 of 12 b128/px) to the near-idle VMEM pipe via a
// 28 KB z-pair-duplicated fp16 table in d_ws (prep kernel, ~2us), L1/L2
// resident. A-only LDS = 36,864 B -> still 2x1024 blocks/CU = 32 waves.
// Identical fp16 values + op order => bit-identical output. Fallback if
// ws too small: read row2 from fp32 grid (same values after cvt).

typedef _Float16 h2 __attribute__((ext_vector_type(2)));
typedef _Float16 h4 __attribute__((ext_vector_type(4)));
typedef _Float16 h8 __attribute__((ext_vector_type(8)));

#define BLOCK 1024

// A: coeffs 0..7: [y][x][z][8]h. XSA=72 (144B, group stride 1 mod 8).
#define XSA 72
#define YSA 1152
#define NA  18432   // 36,864 B

// B table in d_ws: [cell=(y*16+x)][zp=0..6][8]h = {row2[zp], row2[zp+1]}.
// Entry = cell*7 + zp, 16 B each, total 256*7*16 = 28,672 B.
#define BT_BYTES 28672

__global__ void prep_b(const float* __restrict__ grid,
                       _Float16* __restrict__ bt) {
    int zp = blockIdx.x;        // 0..6
    int c  = threadIdx.x;       // 0..255 = y*16+x
    const float4* gr = (const float4*)grid;   // cell*3 float4s per cell
    int cell8 = c * 8;
    float4 lo = gr[(cell8 + zp) * 3 + 2];      // row2 @ z=zp
    float4 hi = gr[(cell8 + zp + 1) * 3 + 2];  // row2 @ z=zp+1
    h8 v = { (_Float16)lo.x, (_Float16)lo.y, (_Float16)lo.z, (_Float16)lo.w,
             (_Float16)hi.x, (_Float16)hi.y, (_Float16)hi.z, (_Float16)hi.w };
    *(h8*)(bt + (c * 7 + zp) * 8) = v;
}

template <bool WS>
__global__ __launch_bounds__(BLOCK) void bilateral_apply(
    const float* __restrict__ pixels,
    const float* __restrict__ coords,
    const float* __restrict__ grid,
    const _Float16* __restrict__ bt,
    float* __restrict__ out,
    int n4)
{
    __shared__ alignas(16) _Float16 gA[NA];  // 36,864 B (A only)

    const int stride = gridDim.x * BLOCK;
    int t = blockIdx.x * BLOCK + threadIdx.x;

    // First quad's loads before staging: HBM latency hides under stage+barrier.
    long long base = (long long)t * 4;
    const float* pp = pixels + base * 3;
    const float* cp = coords + base * 2;
    float4 pa = *(const float4*)(pp + 0);
    float4 pb = *(const float4*)(pp + 4);
    float4 pc = *(const float4*)(pp + 8);
    float4 ca = *(const float4*)(cp + 0);
    float4 cb = *(const float4*)(cp + 4);

    // Cooperative stage: rows 0,1 only -> fp16 LDS.
    for (int cell = threadIdx.x; cell < 2048; cell += BLOCK) {
        int y = cell >> 7;
        int x = (cell >> 3) & 15;
        int z = cell & 7;
        const float4* src = (const float4*)(grid + (long long)cell * 12);
        float4 v0 = src[0], v1 = src[1];
        h8 a = { (_Float16)v0.x, (_Float16)v0.y, (_Float16)v0.z, (_Float16)v0.w,
                 (_Float16)v1.x, (_Float16)v1.y, (_Float16)v1.z, (_Float16)v1.w };
        *(h8*)(gA + y * YSA + x * XSA + z * 8) = a;   // 16B aligned
    }
    __syncthreads();

    #pragma clang loop unroll(disable)
    while (true) {
        // Prefetch next quad while this one computes.
        int tn = t + stride;
        bool more = tn < n4;
        float4 npa, npb, npc, nca, ncb;
        if (more) {
            long long nbase = (long long)tn * 4;
            const float* npp = pixels + nbase * 3;
            const float* ncp = coords + nbase * 2;
            npa = *(const float4*)(npp + 0);
            npb = *(const float4*)(npp + 4);
            npc = *(const float4*)(npp + 8);
            nca = *(const float4*)(ncp + 0);
            ncb = *(const float4*)(ncp + 4);
        }
        __builtin_amdgcn_sched_barrier(0);  // pin prefetch issue above compute

        float R[4]  = {pa.x, pa.w, pb.z, pc.y};
        float G[4]  = {pa.y, pb.x, pb.w, pc.z};
        float Bc[4] = {pa.z, pb.y, pc.x, pc.w};
        float CX[4] = {ca.x, ca.z, cb.x, cb.z};
        float CY[4] = {ca.y, ca.w, cb.y, cb.w};

        #pragma unroll
        for (int k = 0; k < 4; ++k) {
            float r = R[k], g = G[k], b = Bc[k];
            float guide = 0.2126f * r + 0.7152f * g + 0.0722f * b;

            float gx = fminf(fmaxf(CX[k] * 15.0f, 0.0f), 14.999f);
            float gy = fminf(fmaxf(CY[k] * 15.0f, 0.0f), 14.999f);
            float gz = fminf(fminf(fmaxf(guide, 0.0f), 1.0f) * 7.0f, 6.999f);

            int x0 = (int)gx, y0 = (int)gy, z0 = (int)gz;
            float fx = gx - (float)x0;
            float fy = gy - (float)y0;
            float fz = gz - (float)z0;

            int abase = y0 * YSA + x0 * XSA + z0 * 8;

            // ---- B (row 2): issue the 4 corner loads EARLY (VMEM pipe;
            // table is L1/L2-resident). h8 covers both z planes.
            h8 qb[4];
            if constexpr (WS) {
                const h8* bq = (const h8*)bt + ((y0 * 16 + x0) * 7 + z0);
                qb[0] = bq[0];    // (y0,x0)
                qb[1] = bq[7];    // (y0,x1)
                qb[2] = bq[112];  // (y1,x0)
                qb[3] = bq[119];  // (y1,x1)
            } else {
                const float4* gr = (const float4*)grid;
                int c8 = (y0 * 16 + x0) * 8 + z0;
                const int co[4] = {0, 8 * 8, 16 * 8 * 8, 17 * 8 * 8};  // wrong-free: x+1=+8 cells? no: cells are (y*16+x)*8+z; x+1 -> +8, y+1 -> +128
                #pragma unroll
                for (int c = 0; c < 4; ++c) {
                    int cc = c8 + ((c & 1) ? 8 : 0) + ((c & 2) ? 128 : 0);
                    float4 lo = gr[cc * 3 + 2];
                    float4 hi = gr[(cc + 1) * 3 + 2];
                    qb[c] = h8{ (_Float16)lo.x, (_Float16)lo.y, (_Float16)lo.z, (_Float16)lo.w,
                                (_Float16)hi.x, (_Float16)hi.y, (_Float16)hi.z, (_Float16)hi.w };
                }
                (void)co;
            }

            float wz0 = 1.0f - fz, wz1 = fz;
            float cw0 = (1.0f - fy) * (1.0f - fx);
            float cw1 = (1.0f - fy) * fx;
            float cw2 = fy * (1.0f - fx);
            float cw3 = fy * fx;
            h2 w[4] = { h2{(_Float16)(cw0 * wz0), (_Float16)(cw0 * wz1)},
                        h2{(_Float16)(cw1 * wz0), (_Float16)(cw1 * wz1)},
                        h2{(_Float16)(cw2 * wz0), (_Float16)(cw2 * wz1)},
                        h2{(_Float16)(cw3 * wz0), (_Float16)(cw3 * wz1)} };

            const int ao[4] = {0, XSA, YSA, YSA + XSA};
            h8 accA = (h8)(_Float16)0.0f;   // rows 0,1
            h4 accB = (h4)(_Float16)0.0f;   // row 2

            #pragma unroll
            for (int c = 0; c < 4; ++c) {
                const h8* qa = (const h8*)(gA + abase + ao[c]);  // 16B aligned
                h8 a0 = qa[0];   // rows 0,1 @ z0
                h8 a1 = qa[1];   // rows 0,1 @ z1
                _Float16 u0 = w[c].x, u1 = w[c].y;
                h8 u0v8 = {u0, u0, u0, u0, u0, u0, u0, u0};
                h8 u1v8 = {u1, u1, u1, u1, u1, u1, u1, u1};
                accA = a0 * u0v8 + (a1 * u1v8 + accA);           // v_pk_fma_f16
                h4 blo = __builtin_shufflevector(qb[c], qb[c], 0, 1, 2, 3);
                h4 bhi = __builtin_shufflevector(qb[c], qb[c], 4, 5, 6, 7);
                h4 u0v4 = {u0, u0, u0, u0};
                h4 u1v4 = {u1, u1, u1, u1};
                accB = blo * u0v4 + (bhi * u1v4 + accB);
            }

            h4 acc0 = __builtin_shufflevector(accA, accA, 0, 1, 2, 3);
            h4 acc1 = __builtin_shufflevector(accA, accA, 4, 5, 6, 7);
            float o0 = fmaf((float)acc0.x, r, fmaf((float)acc0.y, g,
                       fmaf((float)acc0.z, b, (float)acc0.w)));
            float o1 = fmaf((float)acc1.x, r, fmaf((float)acc1.y, g,
                       fmaf((float)acc1.z, b, (float)acc1.w)));
            float o2 = fmaf((float)accB.x, r, fmaf((float)accB.y, g,
                       fmaf((float)accB.z, b, (float)accB.w)));
            float* op = out + (base + k) * 3;
            op[0] = o0; op[1] = o1; op[2] = o2;
        }

        if (!more) break;
        pa = npa; pb = npb; pc = npc; ca = nca; cb = ncb;
        t = tn;
        base = (long long)t * 4;
    }
}

extern "C" void kernel_launch(void* const* d_in, const int* in_sizes, int n_in,
                              void* d_out, int out_size, void* d_ws, size_t ws_size,
                              hipStream_t stream) {
    const float* pixels = (const float*)d_in[0];
    const float* coords = (const float*)d_in[1];
    const float* grid   = (const float*)d_in[2];
    float* out = (float*)d_out;

    int npix = in_sizes[0] / 3;   // 8,294,400 (divisible by 4)
    int n4   = npix / 4;          // 2,073,600 quads
    int nblk = 512;               // 2 blocks/CU (thread-limited) = 32 waves

    if (d_ws != nullptr && ws_size >= BT_BYTES) {
        _Float16* bt = (_Float16*)d_ws;
        prep_b<<<7, 256, 0, stream>>>(grid, bt);
        bilateral_apply<true><<<nblk, BLOCK, 0, stream>>>(
            pixels, coords, grid, bt, out, n4);
    } else {
        bilateral_apply<false><<<nblk, BLOCK, 0, stream>>>(
            pixels, coords, grid, nullptr, out, n4);
    }
}